// Round 1
// baseline (208.055 us; speedup 1.0000x reference)
//
#include <hip/hip_runtime.h>
#include <hip/hip_fp16.h>

// imgs (8,3,1024,1024) fp32, z (1e6,2) fp32 -> out (8,2) fp32.
// R12 (this round):
//  - precompute: ROWS=4 output rows per block with rolling channel-summed S
//    rows in LDS + 1-row register prefetch. Read traffic 201->126 MB (each
//    raw row was previously fetched twice, by blocks on different XCDs).
//  - gather: 2 pairs (4 points) per loop iteration -> 12 independent record
//    loads + 2 z-loads in flight per thread (was 6+1, ~2 serialized iters).
//  - final_reduce fused away: precompute block 0 zeroes out[16], gather
//    blocks atomicAdd their 16 block-partials (stream-ordered, 16k atomics).
//  - stage LDS buffer XOR-swizzled (idx ^ ((idx>>4)&7)): balances b128
//    write (4t+i) and read (i*256+t) patterns to 8 lanes per 4-bank set.
// T record per pixel unchanged: 64 B = uint4[4]: [0]=Dy(8 half), [1]=Dx,
// [2]=M, [3]=pad -> exactly one cache line per gathered point.

#define NYX 1024
#define NPIX (NYX * NYX)
#define BATCH 8
#define CH 3
#define GB 1024                                  // gather blocks
#define SROW 260                                 // LDS S-row stride (floats)
#define ROWS 4                                   // output rows per precompute block
#define SW(i) ((i) ^ (((i) >> 4) & 7))           // stage swizzle (involution)

__device__ __forceinline__ unsigned pk2(float a, float b) {
    __half2 h = __floats2half2_rn(a, b);
    return *(unsigned*)&h;
}

__device__ __forceinline__ float4 add4(float4 a, float4 b, float4 c) {
    return make_float4(a.x + b.x + c.x, a.y + b.y + c.y,
                       a.z + b.z + c.z, a.w + b.w + c.w);
}

__global__ __launch_bounds__(256, 4) void precompute_kernel(
    const float* __restrict__ imgs, uint4* __restrict__ T,
    float* __restrict__ out)
{
    int bid  = blockIdx.x;
    int y0   = (bid >> 2) * ROWS;
    int x0   = (bid & 3) << 8;                   // 0,256,512,768
    int t    = threadIdx.x;
    int lane = t & 63;
    int g    = t >> 6;                           // group -> batches 2g,2g+1
    int xe   = min(x0 + 256, NYX - 1);           // strip-edge col (x=1023 unread)

    if (bid == 0 && t < 16) out[t] = 0.0f;       // zero for gather's atomics

    __shared__ float sS[BATCH * 2 * SROW];       // ping-pong S rows, 16640 B
    __shared__ uint4 stage[1024];                // 256 records x 64 B

    float4 vA[6], vB[6];
    float  eA[2], eB[2];

    // load raw row yr for this group's 2 batches x 3 channels (6 float4)
    auto load_row = [&](int yr, float4* vv, float* ee) {
        size_t q = (size_t)yr * NYX + x0;
#pragma unroll
        for (int bl = 0; bl < 2; ++bl) {
#pragma unroll
            for (int c = 0; c < CH; ++c) {
                const float* pl = imgs + (size_t)((2 * g + bl) * CH + c) * NPIX;
                vv[bl * 3 + c] = ((const float4*)(pl + q))[lane];
            }
        }
        ee[0] = 0.0f; ee[1] = 0.0f;
        if (lane == 63) {
#pragma unroll
            for (int bl = 0; bl < 2; ++bl) {
#pragma unroll
                for (int c = 0; c < CH; ++c) {
                    const float* pl = imgs + (size_t)((2 * g + bl) * CH + c) * NPIX;
                    ee[bl] += pl[(size_t)yr * NYX + xe];
                }
            }
        }
    };

    // channel-sum and publish one S row at parity sel
    auto store_S = [&](int sel, const float4* vv, const float* ee) {
#pragma unroll
        for (int bl = 0; bl < 2; ++bl) {
            int b = 2 * g + bl;
            float4 s = add4(vv[bl * 3 + 0], vv[bl * 3 + 1], vv[bl * 3 + 2]);
            *(float4*)&sS[(b * 2 + sel) * SROW + 4 * lane] = s;
            if (lane == 63) sS[(b * 2 + sel) * SROW + 256] = ee[bl];
        }
    };

    load_row(y0, vA, eA);
    store_S(0, vA, eA);
    load_row(min(y0 + 1, NYX - 1), vB, eB);

#pragma unroll
    for (int k = 0; k < ROWS; ++k) {
        int cur = (k + 1) & 1;                   // S row y0+k+1
        int pr  = k & 1;                         // S row y0+k
        if (k & 1) store_S(cur, vA, eA);
        else       store_S(cur, vB, eB);
        if (k + 1 < ROWS) {                      // prefetch row y0+k+2 -> regs
            int ynext = min(y0 + k + 2, NYX - 1);
            if (k & 1) load_row(ynext, vB, eB);
            else       load_row(ynext, vA, eA);
        }
        __syncthreads();

        // per-thread record for pixel (y0+k, x0+t)
        float Dy[BATCH], Dx[BATCH], Mm[BATCH];
#pragma unroll
        for (int b = 0; b < BATCH; ++b) {
            float c00 = sS[(b * 2 + pr)  * SROW + t];
            float c01 = sS[(b * 2 + pr)  * SROW + t + 1];
            float c10 = sS[(b * 2 + cur) * SROW + t];
            float c11 = sS[(b * 2 + cur) * SROW + t + 1];
            Dy[b] = c10 - c00;
            Dx[b] = c01 - c00;
            Mm[b] = (c11 - c01) - Dy[b];
        }
        stage[SW(t * 4 + 0)] = make_uint4(pk2(Dy[0], Dy[1]), pk2(Dy[2], Dy[3]),
                                          pk2(Dy[4], Dy[5]), pk2(Dy[6], Dy[7]));
        stage[SW(t * 4 + 1)] = make_uint4(pk2(Dx[0], Dx[1]), pk2(Dx[2], Dx[3]),
                                          pk2(Dx[4], Dx[5]), pk2(Dx[6], Dx[7]));
        stage[SW(t * 4 + 2)] = make_uint4(pk2(Mm[0], Mm[1]), pk2(Mm[2], Mm[3]),
                                          pk2(Mm[4], Mm[5]), pk2(Mm[6], Mm[7]));
        stage[SW(t * 4 + 3)] = make_uint4(0u, 0u, 0u, 0u);
        __syncthreads();

        // coalesced copy-out: 1024 consecutive uint4 (16 KB, full lines)
        size_t base4 = ((size_t)(y0 + k) * NYX + x0) * 4;
#pragma unroll
        for (int i = 0; i < 4; ++i)
            T[base4 + i * 256 + t] = stage[SW(i * 256 + t)];
    }
}

struct PtSetup {
    const uint4* t4;
    float u, v, s;
};

__device__ __forceinline__ PtSetup setup_pt(float zy, float zx,
                                            const uint4* __restrict__ T) {
    PtSetup r;
    float x0y = zy * (float)(NYX - 1);
    float x0x = zx * (float)(NYX - 1);
    bool oob = (x0y < 0.0f) || (x0y > (float)(NYX - 1)) ||
               (x0x < 0.0f) || (x0x > (float)(NYX - 1));
    float cy = fminf(fmaxf(x0y, 0.0f), (float)(NYX - 1));
    float cx = fminf(fmaxf(x0x, 0.0f), (float)(NYX - 1));
    int yg = min((int)cy, NYX - 2);
    int xg = min((int)cx, NYX - 2);
    r.u = cx - (float)xg;
    r.v = cy - (float)yg;
    r.s = oob ? 0.0f : 1.0f;
    r.t4 = T + ((size_t)yg * NYX + xg) * 4;
    return r;
}

__device__ __forceinline__ void accum_pt(PtSetup P, uint4 rDy, uint4 rDx,
                                         uint4 rM, float* acc0, float* acc1) {
    const __half2* hDy = (const __half2*)&rDy;
    const __half2* hDx = (const __half2*)&rDx;
    const __half2* hM  = (const __half2*)&rM;
#pragma unroll
    for (int j = 0; j < 4; ++j) {
        float2 dy = __half22float2(hDy[j]);
        float2 dx = __half22float2(hDx[j]);
        float2 m  = __half22float2(hM[j]);
        acc0[2 * j + 0] += P.s * fmaf(P.u, m.x, dy.x);
        acc0[2 * j + 1] += P.s * fmaf(P.u, m.y, dy.y);
        acc1[2 * j + 0] += P.s * fmaf(P.v, m.x, dx.x);
        acc1[2 * j + 1] += P.s * fmaf(P.v, m.y, dx.y);
    }
}

__global__ __launch_bounds__(256, 4) void gather_kernel(
    const float* __restrict__ z, const uint4* __restrict__ T,
    float* __restrict__ out, int npts)
{
    float acc0[BATCH];
    float acc1[BATCH];
#pragma unroll
    for (int b = 0; b < BATCH; ++b) { acc0[b] = 0.0f; acc1[b] = 0.0f; }

    const float4* z4 = (const float4*)z;
    int npairs = npts >> 1;
    int stride = gridDim.x * blockDim.x;
    int tid = blockIdx.x * blockDim.x + threadIdx.x;

    // 2 pairs (4 points) per iteration: 2 z-loads + 12 record loads in flight
    for (int i = tid; i < npairs; i += 2 * stride) {
        int i2 = i + stride;
        bool has2 = i2 < npairs;
        float4 za = z4[i];
        float4 zb = z4[has2 ? i2 : i];           // clamped dup, zeroed below
        PtSetup A = setup_pt(za.x, za.y, T);
        PtSetup B = setup_pt(za.z, za.w, T);
        PtSetup C = setup_pt(zb.x, zb.y, T);
        PtSetup D = setup_pt(zb.z, zb.w, T);
        if (!has2) { C.s = 0.0f; D.s = 0.0f; }
        uint4 aDy = A.t4[0], aDx = A.t4[1], aM = A.t4[2];
        uint4 bDy = B.t4[0], bDx = B.t4[1], bM = B.t4[2];
        uint4 cDy = C.t4[0], cDx = C.t4[1], cM = C.t4[2];
        uint4 dDy = D.t4[0], dDx = D.t4[1], dM = D.t4[2];
        accum_pt(A, aDy, aDx, aM, acc0, acc1);
        accum_pt(B, bDy, bDx, bM, acc0, acc1);
        accum_pt(C, cDy, cDx, cM, acc0, acc1);
        accum_pt(D, dDy, dDx, dM, acc0, acc1);
    }

    // odd-npts tail (not taken for npts = 1e6)
    if ((npts & 1) && blockIdx.x == 0 && threadIdx.x == 0) {
        float zy = z[2 * (npts - 1)], zx = z[2 * (npts - 1) + 1];
        PtSetup A = setup_pt(zy, zx, T);
        uint4 aDy = A.t4[0], aDx = A.t4[1], aM = A.t4[2];
        accum_pt(A, aDy, aDx, aM, acc0, acc1);
    }

#pragma unroll
    for (int b = 0; b < BATCH; ++b) {
#pragma unroll
        for (int off = 32; off > 0; off >>= 1) {
            acc0[b] += __shfl_down(acc0[b], off, 64);
            acc1[b] += __shfl_down(acc1[b], off, 64);
        }
    }

    __shared__ float sred[4][16];
    int lane = threadIdx.x & 63;
    int wave = threadIdx.x >> 6;
    if (lane == 0) {
#pragma unroll
        for (int b = 0; b < BATCH; ++b) {
            sred[wave][2 * b + 0] = acc0[b];
            sred[wave][2 * b + 1] = acc1[b];
        }
    }
    __syncthreads();
    if (threadIdx.x < 16) {
        float s = sred[0][threadIdx.x] + sred[1][threadIdx.x] +
                  sred[2][threadIdx.x] + sred[3][threadIdx.x];
        atomicAdd(&out[threadIdx.x], s);         // out zeroed by precompute
    }
}

// ---- fallback (round-1 unsorted path) if ws is too small ----
__global__ void zero_out_kernel(float* __restrict__ out) {
    int i = threadIdx.x;
    if (i < 16) out[i] = 0.0f;
}

__global__ __launch_bounds__(256) void interp_grad_kernel(
    const float* __restrict__ imgs, const float* __restrict__ z,
    float* __restrict__ out, int npts)
{
    int p = blockIdx.x * blockDim.x + threadIdx.x;
    float acc0[BATCH];
    float acc1[BATCH];
#pragma unroll
    for (int b = 0; b < BATCH; ++b) { acc0[b] = 0.0f; acc1[b] = 0.0f; }
    if (p < npts) {
        float2 zz = ((const float2*)z)[p];
        float x0y = zz.x * (float)(NYX - 1);
        float x0x = zz.y * (float)(NYX - 1);
        bool oob = (x0y < 0.0f) || (x0y > (float)(NYX - 1)) ||
                   (x0x < 0.0f) || (x0x > (float)(NYX - 1));
        if (!oob) {
            int yg = min((int)floorf(x0y), NYX - 2);
            int xg = min((int)floorf(x0x), NYX - 2);
            float fy = (float)yg - x0y;
            float fx = (float)xg - x0x;
            const float* base = imgs + (size_t)yg * NYX + xg;
#pragma unroll
            for (int b = 0; b < BATCH; ++b) {
#pragma unroll
                for (int c = 0; c < CH; ++c) {
                    const float* pl = base + (size_t)(b * CH + c) * (size_t)NPIX;
                    float g00 = pl[0];
                    float g01 = pl[1];
                    float g10 = pl[NYX];
                    float g11 = pl[NYX + 1];
                    float a1 = g10 - g00;
                    float a2 = g11 - g01;
                    float a3 = g01 - g00;
                    float d  = a1 - a2;
                    acc0[b] += d * fx + a1;
                    acc1[b] += d * fy + a3;
                }
            }
        }
    }
#pragma unroll
    for (int b = 0; b < BATCH; ++b) {
#pragma unroll
        for (int off = 32; off > 0; off >>= 1) {
            acc0[b] += __shfl_down(acc0[b], off, 64);
            acc1[b] += __shfl_down(acc1[b], off, 64);
        }
    }
    __shared__ float sred[4][16];
    int lane = threadIdx.x & 63;
    int wave = threadIdx.x >> 6;
    if (lane == 0) {
#pragma unroll
        for (int b = 0; b < BATCH; ++b) {
            sred[wave][2 * b + 0] = acc0[b];
            sred[wave][2 * b + 1] = acc1[b];
        }
    }
    __syncthreads();
    if (threadIdx.x < 16) {
        float s = sred[0][threadIdx.x] + sred[1][threadIdx.x] +
                  sred[2][threadIdx.x] + sred[3][threadIdx.x];
        atomicAdd(&out[threadIdx.x], s);
    }
}

extern "C" void kernel_launch(void* const* d_in, const int* in_sizes, int n_in,
                              void* d_out, int out_size, void* d_ws, size_t ws_size,
                              hipStream_t stream) {
    const float* imgs = (const float*)d_in[0];
    const float* z    = (const float*)d_in[1];
    float* out        = (float*)d_out;
    int npts = in_sizes[1] / 2;

    size_t ws_need = (size_t)NPIX * 64;          // 64 MB T table

    if (ws_size < ws_need) {
        int blocks = (npts + 255) / 256;
        zero_out_kernel<<<1, 64, 0, stream>>>(out);
        interp_grad_kernel<<<blocks, 256, 0, stream>>>(imgs, z, out, npts);
        return;
    }

    uint4* T = (uint4*)d_ws;

    precompute_kernel<<<(NYX / ROWS) * 4, 256, 0, stream>>>(imgs, T, out);
    gather_kernel<<<GB, 256, 0, stream>>>(z, T, out, npts);
}

// Round 2
// 190.639 us; speedup vs baseline: 1.0914x; 1.0914x over previous
//
#include <hip/hip_runtime.h>
#include <hip/hip_fp16.h>

// imgs (8,3,1024,1024) fp32, z (1e6,2) fp32 -> out (8,2) fp32.
// R13 (this round):
//  - precompute reverted to R11 shape: 1 output row/block, 4096 blocks, all
//    12 float4 loads issued upfront (R12's ROWS=4 rolling variant collapsed
//    to 1024 blocks / 33% occupancy / 1.5 TB/s latency-bound -> 90 us).
//  - NEW: XCD-aware block swizzle. Logical block L = xcd*512 + (bid>>3),
//    strip-major by y: rows (y,s) and (y+1,s) land on the SAME XCD, 8 apart
//    in dispatch order -> the y+1 row segment (24 KB) is L2-hot when the
//    adjacent block reads it as its y row. Dedups the 2x row re-read via L2
//    instead of via block-merging, keeping full 4096-block parallelism.
//  - kept from R12: gather 2-pair unroll (12 record loads in flight), fused
//    final reduce (precompute block 0 zeroes out, gather atomicAdds 16
//    values/block), stage LDS swizzle.
// T record per pixel: 64 B = uint4[4]: [0]=Dy(8 half), [1]=Dx, [2]=M,
// [3]=pad -> exactly one cache line per gathered point.

#define NYX 1024
#define NPIX (NYX * NYX)
#define BATCH 8
#define CH 3
#define GB 1024                                  // gather blocks
#define SROW 260                                 // LDS S-row stride (floats)
#define SW(i) ((i) ^ (((i) >> 4) & 7))           // stage swizzle (involution)

__device__ __forceinline__ unsigned pk2(float a, float b) {
    __half2 h = __floats2half2_rn(a, b);
    return *(unsigned*)&h;
}

__device__ __forceinline__ float4 add4(float4 a, float4 b, float4 c) {
    return make_float4(a.x + b.x + c.x, a.y + b.y + c.y,
                       a.z + b.z + c.z, a.w + b.w + c.w);
}

__global__ __launch_bounds__(256, 4) void precompute_kernel(
    const float* __restrict__ imgs, uint4* __restrict__ T,
    float* __restrict__ out)
{
    // XCD swizzle: 4096 blocks, 8 XCDs (bid&7). Chunk of 512 consecutive
    // logical blocks per XCD, logical order = strip-major by y so adjacent-y
    // blocks share the XCD's L2 for the overlapping row.
    int bid0 = blockIdx.x;
    int L    = ((bid0 & 7) << 9) | (bid0 >> 3);  // bijective on [0,4096)
    int y    = L & 1023;
    int x0   = (L >> 10) << 8;                   // strip 0..3 -> 0,256,512,768
    int t    = threadIdx.x;
    int lane = t & 63;
    int g    = t >> 6;                           // group 0..3 -> batches 2g,2g+1
    int yp   = min(y + 1, NYX - 1);              // y=1023 records garbage, unread
    int xe   = min(x0 + 256, NYX - 1);           // strip-edge col (x=1023 unread)

    if (bid0 == 0 && t < 16) out[t] = 0.0f;      // zero for gather's atomics

    size_t q0 = (size_t)y  * NYX + x0;
    size_t q1 = (size_t)yp * NYX + x0;

    __shared__ float sS[BATCH * 2 * SROW];       // 16640 B: S_b rows y,y+1 + edge
    __shared__ uint4 stage[1024];                // 16384 B: 256 records x 64 B

    // 12 independent float4 loads (2 b x 3 c x 2 rows), distinct registers
    float4 v[12];
#pragma unroll
    for (int bl = 0; bl < 2; ++bl) {
        int b = 2 * g + bl;
#pragma unroll
        for (int c = 0; c < CH; ++c) {
            const float* pl = imgs + (size_t)(b * CH + c) * NPIX;
            v[bl * 6 + c * 2 + 0] = ((const float4*)(pl + q0))[lane];
            v[bl * 6 + c * 2 + 1] = ((const float4*)(pl + q1))[lane];
        }
    }
    float edge[4] = {0.f, 0.f, 0.f, 0.f};
    if (lane == 63) {
#pragma unroll
        for (int bl = 0; bl < 2; ++bl) {
            int b = 2 * g + bl;
#pragma unroll
            for (int c = 0; c < CH; ++c) {
                const float* pl = imgs + (size_t)(b * CH + c) * NPIX;
                edge[bl * 2 + 0] += pl[(size_t)y  * NYX + xe];
                edge[bl * 2 + 1] += pl[(size_t)yp * NYX + xe];
            }
        }
    }

#pragma unroll
    for (int bl = 0; bl < 2; ++bl) {
        int b = 2 * g + bl;
        float4 s0 = add4(v[bl * 6 + 0], v[bl * 6 + 2], v[bl * 6 + 4]);
        float4 s1 = add4(v[bl * 6 + 1], v[bl * 6 + 3], v[bl * 6 + 5]);
        *(float4*)&sS[(b * 2 + 0) * SROW + 4 * lane] = s0;
        *(float4*)&sS[(b * 2 + 1) * SROW + 4 * lane] = s1;
        if (lane == 63) {
            sS[(b * 2 + 0) * SROW + 256] = edge[bl * 2 + 0];
            sS[(b * 2 + 1) * SROW + 256] = edge[bl * 2 + 1];
        }
    }
    __syncthreads();

    // per-thread record for pixel (y, x0+t)
    float Dy[BATCH], Dx[BATCH], Mm[BATCH];
#pragma unroll
    for (int b = 0; b < BATCH; ++b) {
        float c00 = sS[(b * 2 + 0) * SROW + t];
        float c01 = sS[(b * 2 + 0) * SROW + t + 1];
        float c10 = sS[(b * 2 + 1) * SROW + t];
        float c11 = sS[(b * 2 + 1) * SROW + t + 1];
        Dy[b] = c10 - c00;
        Dx[b] = c01 - c00;
        Mm[b] = (c11 - c01) - Dy[b];
    }

    stage[SW(t * 4 + 0)] = make_uint4(pk2(Dy[0], Dy[1]), pk2(Dy[2], Dy[3]),
                                      pk2(Dy[4], Dy[5]), pk2(Dy[6], Dy[7]));
    stage[SW(t * 4 + 1)] = make_uint4(pk2(Dx[0], Dx[1]), pk2(Dx[2], Dx[3]),
                                      pk2(Dx[4], Dx[5]), pk2(Dx[6], Dx[7]));
    stage[SW(t * 4 + 2)] = make_uint4(pk2(Mm[0], Mm[1]), pk2(Mm[2], Mm[3]),
                                      pk2(Mm[4], Mm[5]), pk2(Mm[6], Mm[7]));
    stage[SW(t * 4 + 3)] = make_uint4(0u, 0u, 0u, 0u);
    __syncthreads();

    // coalesced copy-out: 1024 consecutive uint4 (16 KB window, full lines)
    size_t base4 = ((size_t)y * NYX + x0) * 4;
#pragma unroll
    for (int i = 0; i < 4; ++i)
        T[base4 + i * 256 + t] = stage[SW(i * 256 + t)];
}

struct PtSetup {
    const uint4* t4;
    float u, v, s;
};

__device__ __forceinline__ PtSetup setup_pt(float zy, float zx,
                                            const uint4* __restrict__ T) {
    PtSetup r;
    float x0y = zy * (float)(NYX - 1);
    float x0x = zx * (float)(NYX - 1);
    bool oob = (x0y < 0.0f) || (x0y > (float)(NYX - 1)) ||
               (x0x < 0.0f) || (x0x > (float)(NYX - 1));
    float cy = fminf(fmaxf(x0y, 0.0f), (float)(NYX - 1));
    float cx = fminf(fmaxf(x0x, 0.0f), (float)(NYX - 1));
    int yg = min((int)cy, NYX - 2);
    int xg = min((int)cx, NYX - 2);
    r.u = cx - (float)xg;
    r.v = cy - (float)yg;
    r.s = oob ? 0.0f : 1.0f;
    r.t4 = T + ((size_t)yg * NYX + xg) * 4;
    return r;
}

__device__ __forceinline__ void accum_pt(PtSetup P, uint4 rDy, uint4 rDx,
                                         uint4 rM, float* acc0, float* acc1) {
    const __half2* hDy = (const __half2*)&rDy;
    const __half2* hDx = (const __half2*)&rDx;
    const __half2* hM  = (const __half2*)&rM;
#pragma unroll
    for (int j = 0; j < 4; ++j) {
        float2 dy = __half22float2(hDy[j]);
        float2 dx = __half22float2(hDx[j]);
        float2 m  = __half22float2(hM[j]);
        acc0[2 * j + 0] += P.s * fmaf(P.u, m.x, dy.x);
        acc0[2 * j + 1] += P.s * fmaf(P.u, m.y, dy.y);
        acc1[2 * j + 0] += P.s * fmaf(P.v, m.x, dx.x);
        acc1[2 * j + 1] += P.s * fmaf(P.v, m.y, dx.y);
    }
}

__global__ __launch_bounds__(256, 4) void gather_kernel(
    const float* __restrict__ z, const uint4* __restrict__ T,
    float* __restrict__ out, int npts)
{
    float acc0[BATCH];
    float acc1[BATCH];
#pragma unroll
    for (int b = 0; b < BATCH; ++b) { acc0[b] = 0.0f; acc1[b] = 0.0f; }

    const float4* z4 = (const float4*)z;
    int npairs = npts >> 1;
    int stride = gridDim.x * blockDim.x;
    int tid = blockIdx.x * blockDim.x + threadIdx.x;

    // 2 pairs (4 points) per iteration: 2 z-loads + 12 record loads in flight
    for (int i = tid; i < npairs; i += 2 * stride) {
        int i2 = i + stride;
        bool has2 = i2 < npairs;
        float4 za = z4[i];
        float4 zb = z4[has2 ? i2 : i];           // clamped dup, zeroed below
        PtSetup A = setup_pt(za.x, za.y, T);
        PtSetup B = setup_pt(za.z, za.w, T);
        PtSetup C = setup_pt(zb.x, zb.y, T);
        PtSetup D = setup_pt(zb.z, zb.w, T);
        if (!has2) { C.s = 0.0f; D.s = 0.0f; }
        uint4 aDy = A.t4[0], aDx = A.t4[1], aM = A.t4[2];
        uint4 bDy = B.t4[0], bDx = B.t4[1], bM = B.t4[2];
        uint4 cDy = C.t4[0], cDx = C.t4[1], cM = C.t4[2];
        uint4 dDy = D.t4[0], dDx = D.t4[1], dM = D.t4[2];
        accum_pt(A, aDy, aDx, aM, acc0, acc1);
        accum_pt(B, bDy, bDx, bM, acc0, acc1);
        accum_pt(C, cDy, cDx, cM, acc0, acc1);
        accum_pt(D, dDy, dDx, dM, acc0, acc1);
    }

    // odd-npts tail (not taken for npts = 1e6)
    if ((npts & 1) && blockIdx.x == 0 && threadIdx.x == 0) {
        float zy = z[2 * (npts - 1)], zx = z[2 * (npts - 1) + 1];
        PtSetup A = setup_pt(zy, zx, T);
        uint4 aDy = A.t4[0], aDx = A.t4[1], aM = A.t4[2];
        accum_pt(A, aDy, aDx, aM, acc0, acc1);
    }

#pragma unroll
    for (int b = 0; b < BATCH; ++b) {
#pragma unroll
        for (int off = 32; off > 0; off >>= 1) {
            acc0[b] += __shfl_down(acc0[b], off, 64);
            acc1[b] += __shfl_down(acc1[b], off, 64);
        }
    }

    __shared__ float sred[4][16];
    int lane = threadIdx.x & 63;
    int wave = threadIdx.x >> 6;
    if (lane == 0) {
#pragma unroll
        for (int b = 0; b < BATCH; ++b) {
            sred[wave][2 * b + 0] = acc0[b];
            sred[wave][2 * b + 1] = acc1[b];
        }
    }
    __syncthreads();
    if (threadIdx.x < 16) {
        float s = sred[0][threadIdx.x] + sred[1][threadIdx.x] +
                  sred[2][threadIdx.x] + sred[3][threadIdx.x];
        atomicAdd(&out[threadIdx.x], s);         // out zeroed by precompute
    }
}

// ---- fallback (round-1 unsorted path) if ws is too small ----
__global__ void zero_out_kernel(float* __restrict__ out) {
    int i = threadIdx.x;
    if (i < 16) out[i] = 0.0f;
}

__global__ __launch_bounds__(256) void interp_grad_kernel(
    const float* __restrict__ imgs, const float* __restrict__ z,
    float* __restrict__ out, int npts)
{
    int p = blockIdx.x * blockDim.x + threadIdx.x;
    float acc0[BATCH];
    float acc1[BATCH];
#pragma unroll
    for (int b = 0; b < BATCH; ++b) { acc0[b] = 0.0f; acc1[b] = 0.0f; }
    if (p < npts) {
        float2 zz = ((const float2*)z)[p];
        float x0y = zz.x * (float)(NYX - 1);
        float x0x = zz.y * (float)(NYX - 1);
        bool oob = (x0y < 0.0f) || (x0y > (float)(NYX - 1)) ||
                   (x0x < 0.0f) || (x0x > (float)(NYX - 1));
        if (!oob) {
            int yg = min((int)floorf(x0y), NYX - 2);
            int xg = min((int)floorf(x0x), NYX - 2);
            float fy = (float)yg - x0y;
            float fx = (float)xg - x0x;
            const float* base = imgs + (size_t)yg * NYX + xg;
#pragma unroll
            for (int b = 0; b < BATCH; ++b) {
#pragma unroll
                for (int c = 0; c < CH; ++c) {
                    const float* pl = base + (size_t)(b * CH + c) * (size_t)NPIX;
                    float g00 = pl[0];
                    float g01 = pl[1];
                    float g10 = pl[NYX];
                    float g11 = pl[NYX + 1];
                    float a1 = g10 - g00;
                    float a2 = g11 - g01;
                    float a3 = g01 - g00;
                    float d  = a1 - a2;
                    acc0[b] += d * fx + a1;
                    acc1[b] += d * fy + a3;
                }
            }
        }
    }
#pragma unroll
    for (int b = 0; b < BATCH; ++b) {
#pragma unroll
        for (int off = 32; off > 0; off >>= 1) {
            acc0[b] += __shfl_down(acc0[b], off, 64);
            acc1[b] += __shfl_down(acc1[b], off, 64);
        }
    }
    __shared__ float sred[4][16];
    int lane = threadIdx.x & 63;
    int wave = threadIdx.x >> 6;
    if (lane == 0) {
#pragma unroll
        for (int b = 0; b < BATCH; ++b) {
            sred[wave][2 * b + 0] = acc0[b];
            sred[wave][2 * b + 1] = acc1[b];
        }
    }
    __syncthreads();
    if (threadIdx.x < 16) {
        float s = sred[0][threadIdx.x] + sred[1][threadIdx.x] +
                  sred[2][threadIdx.x] + sred[3][threadIdx.x];
        atomicAdd(&out[threadIdx.x], s);
    }
}

extern "C" void kernel_launch(void* const* d_in, const int* in_sizes, int n_in,
                              void* d_out, int out_size, void* d_ws, size_t ws_size,
                              hipStream_t stream) {
    const float* imgs = (const float*)d_in[0];
    const float* z    = (const float*)d_in[1];
    float* out        = (float*)d_out;
    int npts = in_sizes[1] / 2;

    size_t ws_need = (size_t)NPIX * 64;          // 64 MB T table

    if (ws_size < ws_need) {
        int blocks = (npts + 255) / 256;
        zero_out_kernel<<<1, 64, 0, stream>>>(out);
        interp_grad_kernel<<<blocks, 256, 0, stream>>>(imgs, z, out, npts);
        return;
    }

    uint4* T = (uint4*)d_ws;

    precompute_kernel<<<NYX * 4, 256, 0, stream>>>(imgs, T, out);
    gather_kernel<<<GB, 256, 0, stream>>>(z, T, out, npts);
}